// Round 1
// baseline (4997.094 us; speedup 1.0000x reference)
//
#include <hip/hip_runtime.h>
#include <hip/hip_bf16.h>
#include <cstddef>

// Problem constants (match reference)
constexpr int NB    = 16;       // batch
constexpr int NN    = 2000;     // nodes per batch
constexpr int TH    = 24;       // T_HIST
constexpr int TF    = 24;       // T_FCST
constexpr int HID   = 64;
constexpr int NF    = 8;        // features
constexpr int NODES = NB * NN;      // 32000
constexpr int ETOT  = NODES * 32;   // 1,024,000 edges
constexpr int TT    = TH + TF;      // 48

__device__ __forceinline__ float sigmoidf_(float x) { return 1.f / (1.f + __expf(-x)); }
__device__ __forceinline__ float tanhf_(float x) {
    float e = __expf(2.f * x);
    return 1.f - 2.f / (e + 1.f);   // safe at +/-inf
}

// ---------------- setup kernels ----------------
__global__ void k_init(float* __restrict__ hA, float* __restrict__ dis) {
    int i = blockIdx.x * blockDim.x + threadIdx.x;
    if (i < HID * NODES) hA[i] = 0.f;
    if (i < NODES) dis[i] = 0.f;
}

__global__ void k_deg(const int* __restrict__ ei, float* __restrict__ deg) {
    int e = blockIdx.x * blockDim.x + threadIdx.x;
    if (e < ETOT) atomicAdd(&deg[ei[ETOT + e]], 1.0f);
}

__global__ void k_dis(float* __restrict__ dis) {
    int i = blockIdx.x * blockDim.x + threadIdx.x;
    if (i < NODES) {
        float d = dis[i];
        dis[i] = (d > 0.f) ? rsqrtf(fmaxf(d, 1.f)) : 0.f;
    }
}

__global__ void k_norm(const int* __restrict__ ei, const float* __restrict__ dis,
                       float* __restrict__ nrm) {
    int e = blockIdx.x * blockDim.x + threadIdx.x;
    if (e < ETOT) nrm[e] = -(dis[ei[e]] * dis[ei[ETOT + e]]);
}

// ---------------- encoder step ----------------
// grid (125, 8): blockIdx.y = jgroup of 8 output channels. Thread = one node.
// Reads h from h_in (k-major [HID][NODES]), writes h_out + H (bf16, per-node contiguous).
__global__ __launch_bounds__(256) void k_enc(
    const float* __restrict__ pm,
    const float* __restrict__ w_ih, const float* __restrict__ w_hh,
    const float* __restrict__ b_ih, const float* __restrict__ b_hh,
    const float* __restrict__ fc_w, const float* __restrict__ fc_b,
    const float* __restrict__ h_in, float* __restrict__ h_out,
    __hip_bfloat16* __restrict__ Hb, int t)
{
    const int node = blockIdx.x * 256 + threadIdx.x;
    if (node >= NODES) return;
    const int jg = blockIdx.y;

    float h[HID];
    #pragma unroll
    for (int k = 0; k < HID; k++) h[k] = h_in[k * NODES + node];

    float xn = 0.f;
    if (t > 0) {
        float acc = fc_b[0];
        #pragma unroll
        for (int k = 0; k < HID; k++) acc += fc_w[k] * h[k];
        xn = acc;
    }
    const int b = node / NN, n = node - b * NN;
    const float pmv = pm[(b * TH + t) * NN + n];

    #pragma unroll
    for (int m = 0; m < 8; m++) {
        const int j = jg * 8 + m;
        float gr = b_ih[j]       + w_ih[2 * j] * xn         + w_ih[2 * j + 1] * pmv;
        float gz = b_ih[64 + j]  + w_ih[2 * (64 + j)] * xn  + w_ih[2 * (64 + j) + 1] * pmv;
        float gn = b_ih[128 + j] + w_ih[2 * (128 + j)] * xn + w_ih[2 * (128 + j) + 1] * pmv;
        float hr = b_hh[j], hz = b_hh[64 + j], hn = b_hh[128 + j];
        const float* wr = w_hh + j * HID;
        const float* wz = w_hh + (64 + j) * HID;
        const float* wn = w_hh + (128 + j) * HID;
        #pragma unroll
        for (int k = 0; k < HID; k++) {
            hr += wr[k] * h[k];
            hz += wz[k] * h[k];
            hn += wn[k] * h[k];
        }
        float r   = sigmoidf_(gr + hr);
        float z   = sigmoidf_(gz + hz);
        float nn_ = tanhf_(gn + r * hn);
        // reload old h[j] from global (avoid runtime-indexed register array -> scratch)
        float hold = h_in[j * NODES + node];
        float hv = (1.f - z) * nn_ + z * hold;
        h_out[j * NODES + node] = hv;
        Hb[(size_t)node * (TH * HID) + t * HID + j] = __float2bfloat16(hv);
    }
}

// after encoder: xn0 = fc(h_final); y1 for decoder t=0; zero tx
__global__ __launch_bounds__(256) void k_fc(
    const float* __restrict__ h_in, const float* __restrict__ fc_w,
    const float* __restrict__ fc_b, const float* __restrict__ feat,
    const float* __restrict__ cw1, float* __restrict__ xn_buf,
    float* __restrict__ y1, float* __restrict__ tx)
{
    const int node = blockIdx.x * 256 + threadIdx.x;
    if (node >= NODES) return;
    float acc = fc_b[0];
    #pragma unroll
    for (int k = 0; k < HID; k++) acc += fc_w[k] * h_in[k * NODES + node];
    xn_buf[node] = acc;
    tx[node] = 0.f;
    const int b = node / NN, n = node - b * NN;
    const float* fp = feat + ((size_t)(b * TT + TH) * NN + n) * NF;
    float yy = acc * cw1[0];
    #pragma unroll
    for (int c = 0; c < NF; c++) yy += fp[c] * cw1[1 + c];
    y1[node] = yy;
}

// ---------------- decoder kernels ----------------
__global__ void k_scatter(const int* __restrict__ ei, const float* __restrict__ nrm,
                          const float* __restrict__ y1, float* __restrict__ tx)
{
    int e = blockIdx.x * blockDim.x + threadIdx.x;
    if (e < ETOT) {
        float v = nrm[e] * y1[ei[e]];
        atomicAdd(&tx[ei[ETOT + e]], v);
    }
}

__global__ __launch_bounds__(256) void k_dgru(
    const float* __restrict__ feat,
    const float* __restrict__ w_ih, const float* __restrict__ w_hh,
    const float* __restrict__ b_ih, const float* __restrict__ b_hh,
    const float* __restrict__ w0, const float* __restrict__ cb,
    const float* __restrict__ xn_buf, const float* __restrict__ tx,
    const float* __restrict__ h_in, float* __restrict__ h_out,
    float* __restrict__ h_nm, int t)
{
    const int node = blockIdx.x * 256 + threadIdx.x;
    if (node >= NODES) return;
    const int jg = blockIdx.y;

    float h[HID];
    #pragma unroll
    for (int k = 0; k < HID; k++) h[k] = h_in[k * NODES + node];

    const int b = node / NN, n = node - b * NN;
    const float xnv = xn_buf[node];
    float f[NF];
    const float* fp = feat + ((size_t)(b * TT + TH + t) * NN + n) * NF;
    #pragma unroll
    for (int c = 0; c < NF; c++) f[c] = fp[c];

    float xw0 = xnv * w0[0];
    #pragma unroll
    for (int c = 0; c < NF; c++) xw0 += f[c] * w0[1 + c];
    const float xg = sigmoidf_(xw0 + tx[node] + cb[0]);

    #pragma unroll
    for (int m = 0; m < 8; m++) {
        const int j = jg * 8 + m;
        float gr = b_ih[j], gz = b_ih[64 + j], gn = b_ih[128 + j];
        const float* ir  = w_ih + j * 10;
        const float* iz  = w_ih + (64 + j) * 10;
        const float* in_ = w_ih + (128 + j) * 10;
        gr += ir[0] * xnv; gz += iz[0] * xnv; gn += in_[0] * xnv;
        #pragma unroll
        for (int c = 0; c < NF; c++) {
            gr += ir[1 + c] * f[c]; gz += iz[1 + c] * f[c]; gn += in_[1 + c] * f[c];
        }
        gr += ir[9] * xg; gz += iz[9] * xg; gn += in_[9] * xg;

        float hr = b_hh[j], hz = b_hh[64 + j], hn = b_hh[128 + j];
        const float* wr = w_hh + j * HID;
        const float* wz = w_hh + (64 + j) * HID;
        const float* wn = w_hh + (128 + j) * HID;
        #pragma unroll
        for (int k = 0; k < HID; k++) {
            hr += wr[k] * h[k];
            hz += wz[k] * h[k];
            hn += wn[k] * h[k];
        }
        float r   = sigmoidf_(gr + hr);
        float z   = sigmoidf_(gz + hz);
        float nn_ = tanhf_(gn + r * hn);
        float hold = h_in[j * NODES + node];
        float hv = (1.f - z) * nn_ + z * hold;
        h_out[j * NODES + node] = hv;
        h_nm[node * HID + j] = hv;
    }
}

// attention + out-projection + (y1, tx) prep for next step. Wave per node.
__global__ __launch_bounds__(256) void k_attn(
    const __hip_bfloat16* __restrict__ Hb, const float* __restrict__ h_nm,
    const float* __restrict__ out_w, const float* __restrict__ out_b,
    const float* __restrict__ feat, const float* __restrict__ cw1,
    float* __restrict__ xn_buf, float* __restrict__ y1, float* __restrict__ tx,
    float* __restrict__ out, int t)
{
    const int wid  = threadIdx.x >> 6;
    const int lane = threadIdx.x & 63;
    const int node = blockIdx.x * 4 + wid;
    if (node >= NODES) return;

    const float hj = h_nm[node * HID + lane];
    const __hip_bfloat16* Hrow = Hb + (size_t)node * (TH * HID);

    float e[TH];
    #pragma unroll
    for (int tt = 0; tt < TH; tt++) {
        float p = __bfloat162float(Hrow[tt * HID + lane]) * hj;
        #pragma unroll
        for (int off = 32; off >= 1; off >>= 1) p += __shfl_xor(p, off, 64);
        e[tt] = p;   // wave-uniform after butterfly
    }
    float mmax = e[0];
    #pragma unroll
    for (int tt = 1; tt < TH; tt++) mmax = fmaxf(mmax, e[tt]);
    float s = 0.f, a = 0.f;
    #pragma unroll
    for (int tt = 0; tt < TH; tt++) {
        float w = __expf(e[tt] - mmax);
        s += w;
        a += w * __bfloat162float(Hrow[tt * HID + lane]);
    }
    a /= s;

    float p = out_w[lane] * a + out_w[HID + lane] * hj;
    #pragma unroll
    for (int off = 32; off >= 1; off >>= 1) p += __shfl_xor(p, off, 64);
    const float xnew = p + out_b[0];

    if (lane == 0) {
        const int b = node / NN, n = node - b * NN;
        out[(b * TF + t) * NN + n] = xnew;
        xn_buf[node] = xnew;
        tx[node] = 0.f;
        if (t + 1 < TF) {
            const float* fp = feat + ((size_t)(b * TT + TH + t + 1) * NN + n) * NF;
            float yy = xnew * cw1[0];
            #pragma unroll
            for (int c = 0; c < NF; c++) yy += fp[c] * cw1[1 + c];
            y1[node] = yy;
        }
    }
}

// ---------------- host launch ----------------
extern "C" void kernel_launch(void* const* d_in, const int* in_sizes, int n_in,
                              void* d_out, int out_size, void* d_ws, size_t ws_size,
                              hipStream_t stream)
{
    const float* pm     = (const float*)d_in[0];
    const float* feat   = (const float*)d_in[1];
    const int*   ei     = (const int*)d_in[2];
    const float* w_ih_e = (const float*)d_in[3];
    const float* w_hh_e = (const float*)d_in[4];
    const float* b_ih_e = (const float*)d_in[5];
    const float* b_hh_e = (const float*)d_in[6];
    const float* fc_w   = (const float*)d_in[7];
    const float* fc_b   = (const float*)d_in[8];
    const float* cw0    = (const float*)d_in[9];
    const float* cw1    = (const float*)d_in[10];
    const float* cb     = (const float*)d_in[11];
    const float* w_ih_d = (const float*)d_in[12];
    const float* w_hh_d = (const float*)d_in[13];
    const float* b_ih_d = (const float*)d_in[14];
    const float* b_hh_d = (const float*)d_in[15];
    const float* out_w  = (const float*)d_in[16];
    const float* out_b  = (const float*)d_in[17];
    float* out = (float*)d_out;

    char* ws = (char*)d_ws;
    size_t off = 0;
    auto alloc = [&](size_t bytes) -> void* {
        void* p = ws + off;
        off += (bytes + 255) & ~(size_t)255;
        return p;
    };
    float* hA   = (float*)alloc(sizeof(float) * HID * NODES);
    float* hB   = (float*)alloc(sizeof(float) * HID * NODES);
    float* h_nm = (float*)alloc(sizeof(float) * HID * NODES);
    __hip_bfloat16* Hb = (__hip_bfloat16*)alloc(sizeof(__hip_bfloat16) * (size_t)NODES * TH * HID);
    float* xn  = (float*)alloc(sizeof(float) * NODES);
    float* dis = (float*)alloc(sizeof(float) * NODES);
    float* y1  = (float*)alloc(sizeof(float) * NODES);
    float* tx  = (float*)alloc(sizeof(float) * NODES);
    float* nrm = (float*)alloc(sizeof(float) * ETOT);
    if (off > ws_size) return;  // visible failure instead of corruption

    // setup: zero h0, degree -> dis -> edge norms
    k_init<<<(HID * NODES + 255) / 256, 256, 0, stream>>>(hA, dis);
    k_deg<<<(ETOT + 255) / 256, 256, 0, stream>>>(ei, dis);
    k_dis<<<(NODES + 255) / 256, 256, 0, stream>>>(dis);
    k_norm<<<(ETOT + 255) / 256, 256, 0, stream>>>(ei, dis, nrm);

    dim3 gGRU(NODES / 256, 8);

    // encoder: ping-pong hA/hB; 24 steps ends back in hA
    for (int t = 0; t < TH; t++) {
        const float* hin = (t & 1) ? hB : hA;
        float* hout      = (t & 1) ? hA : hB;
        k_enc<<<gGRU, 256, 0, stream>>>(pm, w_ih_e, w_hh_e, b_ih_e, b_hh_e,
                                        fc_w, fc_b, hin, hout, Hb, t);
    }
    k_fc<<<NODES / 256, 256, 0, stream>>>(hA, fc_w, fc_b, feat, cw1, xn, y1, tx);

    // decoder
    for (int t = 0; t < TF; t++) {
        const float* hin = (t & 1) ? hB : hA;
        float* hout      = (t & 1) ? hA : hB;
        k_scatter<<<(ETOT + 255) / 256, 256, 0, stream>>>(ei, nrm, y1, tx);
        k_dgru<<<gGRU, 256, 0, stream>>>(feat, w_ih_d, w_hh_d, b_ih_d, b_hh_d,
                                         cw0, cb, xn, tx, hin, hout, h_nm, t);
        k_attn<<<NODES / 4, 256, 0, stream>>>(Hb, h_nm, out_w, out_b, feat, cw1,
                                              xn, y1, tx, out, t);
    }
}

// Round 2
// 3640.027 us; speedup vs baseline: 1.3728x; 1.3728x over previous
//
#include <hip/hip_runtime.h>
#include <hip/hip_bf16.h>
#include <cstddef>

// Problem constants (match reference)
constexpr int NB    = 16;       // batch
constexpr int NN    = 2000;     // nodes per batch
constexpr int TH    = 24;       // T_HIST
constexpr int TF    = 24;       // T_FCST
constexpr int HID   = 64;
constexpr int NF    = 8;        // features
constexpr int NODES = NB * NN;      // 32000
constexpr int ETOT  = NODES * 32;   // 1,024,000 edges
constexpr int TT    = TH + TF;      // 48
constexpr int NCH   = 128;          // node chunks of 256 (padded: 125 real)

__device__ __forceinline__ float sigmoidf_(float x) { return 1.f / (1.f + __expf(-x)); }
__device__ __forceinline__ float tanhf_(float x) {
    float e = __expf(2.f * x);
    return 1.f - 2.f / (e + 1.f);   // safe at +/-inf
}

// Decode swizzled 1D block id -> (chunk c, jgroup jg) such that all 8 jgroups
// of a chunk share (id % 8)  => same XCD under round-robin dispatch.
__device__ __forceinline__ void swz(int id, int& c, int& jg) {
    int low = id & 7;       // xcd
    int q   = id >> 3;      // [0,128)
    jg      = q >> 4;       // [0,8)
    int chi = q & 15;       // [0,16)
    c       = chi * 8 + low;
}

// ---------------- setup kernels ----------------
__global__ void k_init(float* __restrict__ hA, float* __restrict__ dis) {
    int i = blockIdx.x * blockDim.x + threadIdx.x;
    if (i < HID * NODES) hA[i] = 0.f;
    if (i < NODES) dis[i] = 0.f;
}

__global__ void k_deg(const int* __restrict__ ei, float* __restrict__ deg) {
    int e = blockIdx.x * blockDim.x + threadIdx.x;
    if (e < ETOT) atomicAdd(&deg[ei[ETOT + e]], 1.0f);
}

__global__ void k_dis(float* __restrict__ dis) {
    int i = blockIdx.x * blockDim.x + threadIdx.x;
    if (i < NODES) {
        float d = dis[i];
        dis[i] = (d > 0.f) ? rsqrtf(fmaxf(d, 1.f)) : 0.f;
    }
}

__global__ void k_norm(const int* __restrict__ ei, const float* __restrict__ dis,
                       float* __restrict__ nrm) {
    int e = blockIdx.x * blockDim.x + threadIdx.x;
    if (e < ETOT) nrm[e] = -(dis[ei[e]] * dis[ei[ETOT + e]]);
}

// transpose w_hh (192x64, row-major) -> Wt (64x192, k-major)
__global__ void k_prep(const float* __restrict__ whe, const float* __restrict__ whd,
                       float* __restrict__ Wte, float* __restrict__ Wtd) {
    int i = blockIdx.x * blockDim.x + threadIdx.x;   // i = k*192 + g
    if (i < 192 * 64) {
        int k = i / 192, g = i - k * 192;
        Wte[i] = whe[g * 64 + k];
        Wtd[i] = whd[g * 64 + k];
    }
}

// ---------------- encoder step ----------------
// 1D grid of 1024 blocks (swizzled). Thread = one node, 8 output channels.
// Outer-product over k: 1 coalesced h load + 24 FMA (+1 for xn) per k.
__global__ __launch_bounds__(256) void k_enc(
    const float* __restrict__ pm,
    const float* __restrict__ w_ih, const float* __restrict__ Wt,
    const float* __restrict__ b_ih, const float* __restrict__ b_hh,
    const float* __restrict__ fc_w, const float* __restrict__ fc_b,
    const float* __restrict__ h_in, float* __restrict__ h_out,
    __hip_bfloat16* __restrict__ Hb, int t)
{
    int c, jg;
    swz(blockIdx.x, c, jg);
    const int node = c * 256 + threadIdx.x;
    if (node >= NODES) return;
    const int j0 = jg * 8;

    float accr[8], accz[8], accn[8];
    #pragma unroll
    for (int m = 0; m < 8; m++) {
        accr[m] = b_hh[j0 + m];
        accz[m] = b_hh[64 + j0 + m];
        accn[m] = b_hh[128 + j0 + m];
    }
    float axn = 0.f;
    const float* hp = h_in + node;
    #pragma unroll 4
    for (int k = 0; k < HID; k++) {
        const float hk = hp[(size_t)k * NODES];
        const float* w = Wt + k * 192 + j0;
        #pragma unroll
        for (int m = 0; m < 8; m++) {
            accr[m] = fmaf(w[m],       hk, accr[m]);
            accz[m] = fmaf(w[64 + m],  hk, accz[m]);
            accn[m] = fmaf(w[128 + m], hk, accn[m]);
        }
        axn = fmaf(fc_w[k], hk, axn);
    }
    const float xn = (t > 0) ? (axn + fc_b[0]) : 0.f;

    const int b = node / NN, n = node - b * NN;
    const float pmv = pm[(b * TH + t) * NN + n];

    #pragma unroll
    for (int m = 0; m < 8; m++) {
        const int j = j0 + m;
        float gr = b_ih[j]       + w_ih[2 * j] * xn         + w_ih[2 * j + 1] * pmv;
        float gz = b_ih[64 + j]  + w_ih[2 * (64 + j)] * xn  + w_ih[2 * (64 + j) + 1] * pmv;
        float gn = b_ih[128 + j] + w_ih[2 * (128 + j)] * xn + w_ih[2 * (128 + j) + 1] * pmv;
        float r   = sigmoidf_(gr + accr[m]);
        float z   = sigmoidf_(gz + accz[m]);
        float nn_ = tanhf_(gn + r * accn[m]);
        float hold = h_in[(size_t)j * NODES + node];
        float hv = (1.f - z) * nn_ + z * hold;
        h_out[(size_t)j * NODES + node] = hv;
        Hb[(size_t)node * (TH * HID) + t * HID + j] = __float2bfloat16(hv);
    }
}

// after encoder: xn0 = fc(h_final); y1 for decoder t=0; zero tx
__global__ __launch_bounds__(256) void k_fc(
    const float* __restrict__ h_in, const float* __restrict__ fc_w,
    const float* __restrict__ fc_b, const float* __restrict__ feat,
    const float* __restrict__ cw1, float* __restrict__ xn_buf,
    float* __restrict__ y1, float* __restrict__ tx)
{
    const int node = blockIdx.x * 256 + threadIdx.x;
    if (node >= NODES) return;
    float acc = fc_b[0];
    for (int k = 0; k < HID; k++) acc += fc_w[k] * h_in[(size_t)k * NODES + node];
    xn_buf[node] = acc;
    tx[node] = 0.f;
    const int b = node / NN, n = node - b * NN;
    const float* fp = feat + ((size_t)(b * TT + TH) * NN + n) * NF;
    float yy = acc * cw1[0];
    #pragma unroll
    for (int c = 0; c < NF; c++) yy += fp[c] * cw1[1 + c];
    y1[node] = yy;
}

// ---------------- decoder kernels ----------------
__global__ void k_scatter(const int* __restrict__ ei, const float* __restrict__ nrm,
                          const float* __restrict__ y1, float* __restrict__ tx)
{
    int e = blockIdx.x * blockDim.x + threadIdx.x;
    if (e < ETOT) {
        float v = nrm[e] * y1[ei[e]];
        atomicAdd(&tx[ei[ETOT + e]], v);
    }
}

__global__ __launch_bounds__(256) void k_dgru(
    const float* __restrict__ feat,
    const float* __restrict__ w_ih, const float* __restrict__ Wt,
    const float* __restrict__ b_ih, const float* __restrict__ b_hh,
    const float* __restrict__ w0, const float* __restrict__ cb,
    const float* __restrict__ xn_buf, const float* __restrict__ tx,
    const float* __restrict__ h_in, float* __restrict__ h_out,
    float* __restrict__ h_nm, int t)
{
    int c, jg;
    swz(blockIdx.x, c, jg);
    const int node = c * 256 + threadIdx.x;
    if (node >= NODES) return;
    const int j0 = jg * 8;

    float accr[8], accz[8], accn[8];
    #pragma unroll
    for (int m = 0; m < 8; m++) {
        accr[m] = b_hh[j0 + m];
        accz[m] = b_hh[64 + j0 + m];
        accn[m] = b_hh[128 + j0 + m];
    }
    const float* hp = h_in + node;
    #pragma unroll 4
    for (int k = 0; k < HID; k++) {
        const float hk = hp[(size_t)k * NODES];
        const float* w = Wt + k * 192 + j0;
        #pragma unroll
        for (int m = 0; m < 8; m++) {
            accr[m] = fmaf(w[m],       hk, accr[m]);
            accz[m] = fmaf(w[64 + m],  hk, accz[m]);
            accn[m] = fmaf(w[128 + m], hk, accn[m]);
        }
    }

    const int b = node / NN, n = node - b * NN;
    const float xnv = xn_buf[node];
    float f[NF];
    const float* fp = feat + ((size_t)(b * TT + TH + t) * NN + n) * NF;
    #pragma unroll
    for (int q = 0; q < NF; q++) f[q] = fp[q];

    float xw0 = xnv * w0[0];
    #pragma unroll
    for (int q = 0; q < NF; q++) xw0 = fmaf(f[q], w0[1 + q], xw0);
    const float xg = sigmoidf_(xw0 + tx[node] + cb[0]);

    #pragma unroll
    for (int m = 0; m < 8; m++) {
        const int j = j0 + m;
        const float* ir  = w_ih + j * 10;
        const float* iz  = w_ih + (64 + j) * 10;
        const float* in_ = w_ih + (128 + j) * 10;
        float gr = b_ih[j]       + ir[0] * xnv;
        float gz = b_ih[64 + j]  + iz[0] * xnv;
        float gn = b_ih[128 + j] + in_[0] * xnv;
        #pragma unroll
        for (int q = 0; q < NF; q++) {
            gr = fmaf(ir[1 + q],  f[q], gr);
            gz = fmaf(iz[1 + q],  f[q], gz);
            gn = fmaf(in_[1 + q], f[q], gn);
        }
        gr = fmaf(ir[9],  xg, gr);
        gz = fmaf(iz[9],  xg, gz);
        gn = fmaf(in_[9], xg, gn);

        float r   = sigmoidf_(gr + accr[m]);
        float z   = sigmoidf_(gz + accz[m]);
        float nn_ = tanhf_(gn + r * accn[m]);
        float hold = h_in[(size_t)j * NODES + node];
        float hv = (1.f - z) * nn_ + z * hold;
        h_out[(size_t)j * NODES + node] = hv;
        h_nm[(size_t)node * HID + j] = hv;
    }
}

// attention + out-projection + (y1, tx) prep for next step. Wave per node.
__global__ __launch_bounds__(256) void k_attn(
    const __hip_bfloat16* __restrict__ Hb, const float* __restrict__ h_nm,
    const float* __restrict__ out_w, const float* __restrict__ out_b,
    const float* __restrict__ feat, const float* __restrict__ cw1,
    float* __restrict__ xn_buf, float* __restrict__ y1, float* __restrict__ tx,
    float* __restrict__ out, int t)
{
    const int wid  = threadIdx.x >> 6;
    const int lane = threadIdx.x & 63;
    const int node = blockIdx.x * 4 + wid;
    if (node >= NODES) return;

    const float hj = h_nm[(size_t)node * HID + lane];
    const __hip_bfloat16* Hrow = Hb + (size_t)node * (TH * HID);

    float e[TH];
    #pragma unroll
    for (int tt = 0; tt < TH; tt++) {
        float p = __bfloat162float(Hrow[tt * HID + lane]) * hj;
        #pragma unroll
        for (int off = 32; off >= 1; off >>= 1) p += __shfl_xor(p, off, 64);
        e[tt] = p;   // wave-uniform after butterfly
    }
    float mmax = e[0];
    #pragma unroll
    for (int tt = 1; tt < TH; tt++) mmax = fmaxf(mmax, e[tt]);
    float s = 0.f, a = 0.f;
    #pragma unroll
    for (int tt = 0; tt < TH; tt++) {
        float w = __expf(e[tt] - mmax);
        s += w;
        a += w * __bfloat162float(Hrow[tt * HID + lane]);
    }
    a /= s;

    float p = out_w[lane] * a + out_w[HID + lane] * hj;
    #pragma unroll
    for (int off = 32; off >= 1; off >>= 1) p += __shfl_xor(p, off, 64);
    const float xnew = p + out_b[0];

    if (lane == 0) {
        const int b = node / NN, n = node - b * NN;
        out[(b * TF + t) * NN + n] = xnew;
        xn_buf[node] = xnew;
        tx[node] = 0.f;
        if (t + 1 < TF) {
            const float* fp = feat + ((size_t)(b * TT + TH + t + 1) * NN + n) * NF;
            float yy = xnew * cw1[0];
            #pragma unroll
            for (int c = 0; c < NF; c++) yy += fp[c] * cw1[1 + c];
            y1[node] = yy;
        }
    }
}

// ---------------- host launch ----------------
extern "C" void kernel_launch(void* const* d_in, const int* in_sizes, int n_in,
                              void* d_out, int out_size, void* d_ws, size_t ws_size,
                              hipStream_t stream)
{
    const float* pm     = (const float*)d_in[0];
    const float* feat   = (const float*)d_in[1];
    const int*   ei     = (const int*)d_in[2];
    const float* w_ih_e = (const float*)d_in[3];
    const float* w_hh_e = (const float*)d_in[4];
    const float* b_ih_e = (const float*)d_in[5];
    const float* b_hh_e = (const float*)d_in[6];
    const float* fc_w   = (const float*)d_in[7];
    const float* fc_b   = (const float*)d_in[8];
    const float* cw0    = (const float*)d_in[9];
    const float* cw1    = (const float*)d_in[10];
    const float* cb     = (const float*)d_in[11];
    const float* w_ih_d = (const float*)d_in[12];
    const float* w_hh_d = (const float*)d_in[13];
    const float* b_ih_d = (const float*)d_in[14];
    const float* b_hh_d = (const float*)d_in[15];
    const float* out_w  = (const float*)d_in[16];
    const float* out_b  = (const float*)d_in[17];
    float* out = (float*)d_out;

    char* ws = (char*)d_ws;
    size_t off = 0;
    auto alloc = [&](size_t bytes) -> void* {
        void* p = ws + off;
        off += (bytes + 255) & ~(size_t)255;
        return p;
    };
    float* hA   = (float*)alloc(sizeof(float) * HID * NODES);
    float* hB   = (float*)alloc(sizeof(float) * HID * NODES);
    float* h_nm = (float*)alloc(sizeof(float) * HID * NODES);
    __hip_bfloat16* Hb = (__hip_bfloat16*)alloc(sizeof(__hip_bfloat16) * (size_t)NODES * TH * HID);
    float* xn   = (float*)alloc(sizeof(float) * NODES);
    float* dis  = (float*)alloc(sizeof(float) * NODES);
    float* y1   = (float*)alloc(sizeof(float) * NODES);
    float* tx   = (float*)alloc(sizeof(float) * NODES);
    float* nrm  = (float*)alloc(sizeof(float) * ETOT);
    float* WtE  = (float*)alloc(sizeof(float) * 192 * 64);
    float* WtD  = (float*)alloc(sizeof(float) * 192 * 64);
    if (off > ws_size) return;  // visible failure instead of corruption

    // setup: zero h0, degree -> dis -> edge norms, weight transposes
    k_init<<<(HID * NODES + 255) / 256, 256, 0, stream>>>(hA, dis);
    k_deg<<<(ETOT + 255) / 256, 256, 0, stream>>>(ei, dis);
    k_dis<<<(NODES + 255) / 256, 256, 0, stream>>>(dis);
    k_norm<<<(ETOT + 255) / 256, 256, 0, stream>>>(ei, dis, nrm);
    k_prep<<<(192 * 64 + 255) / 256, 256, 0, stream>>>(w_hh_e, w_hh_d, WtE, WtD);

    const int gGRU = NCH * 8;   // 1024 swizzled blocks

    // encoder: ping-pong hA/hB; 24 steps ends back in hA
    for (int t = 0; t < TH; t++) {
        const float* hin = (t & 1) ? hB : hA;
        float* hout      = (t & 1) ? hA : hB;
        k_enc<<<gGRU, 256, 0, stream>>>(pm, w_ih_e, WtE, b_ih_e, b_hh_e,
                                        fc_w, fc_b, hin, hout, Hb, t);
    }
    k_fc<<<NODES / 256, 256, 0, stream>>>(hA, fc_w, fc_b, feat, cw1, xn, y1, tx);

    // decoder
    for (int t = 0; t < TF; t++) {
        const float* hin = (t & 1) ? hB : hA;
        float* hout      = (t & 1) ? hA : hB;
        k_scatter<<<(ETOT + 255) / 256, 256, 0, stream>>>(ei, nrm, y1, tx);
        k_dgru<<<gGRU, 256, 0, stream>>>(feat, w_ih_d, WtD, b_ih_d, b_hh_d,
                                         cw0, cb, xn, tx, hin, hout, h_nm, t);
        k_attn<<<NODES / 4, 256, 0, stream>>>(Hb, h_nm, out_w, out_b, feat, cw1,
                                              xn, y1, tx, out, t);
    }
}

// Round 3
// 2855.419 us; speedup vs baseline: 1.7500x; 1.2748x over previous
//
#include <hip/hip_runtime.h>
#include <hip/hip_bf16.h>
#include <cstddef>
#include <cstdint>

// Problem constants (match reference)
constexpr int NB    = 16;       // batch
constexpr int NN    = 2000;     // nodes per batch
constexpr int TH    = 24;       // T_HIST
constexpr int TF    = 24;       // T_FCST
constexpr int HID   = 64;
constexpr int NF    = 8;        // features
constexpr int NODES = NB * NN;      // 32000
constexpr int ETOT  = NODES * 32;   // 1,024,000 edges
constexpr int TT    = TH + TF;      // 48
constexpr int NCH   = 128;          // node chunks of 256 (padded: 125 real)

__device__ __forceinline__ float sigmoidf_(float x) { return 1.f / (1.f + __expf(-x)); }
__device__ __forceinline__ float tanhf_(float x) {
    float e = __expf(2.f * x);
    return 1.f - 2.f / (e + 1.f);   // safe at +/-inf
}

// Decode swizzled 1D block id -> (chunk c, jgroup jg) such that all 8 jgroups
// of a chunk share (id % 8)  => same XCD under round-robin dispatch.
__device__ __forceinline__ void swz(int id, int& c, int& jg) {
    int low = id & 7;       // xcd
    int q   = id >> 3;      // [0,128)
    jg      = q >> 4;       // [0,8)
    int chi = q & 15;       // [0,16)
    c       = chi * 8 + low;
}

// ---------------- setup kernels ----------------
__global__ void k_init(float* __restrict__ hA, float* __restrict__ dis) {
    int i = blockIdx.x * blockDim.x + threadIdx.x;
    if (i < HID * NODES) hA[i] = 0.f;
    if (i < NODES) dis[i] = 0.f;
}

__global__ void k_deg(const int* __restrict__ ei, float* __restrict__ deg) {
    int e = blockIdx.x * blockDim.x + threadIdx.x;
    if (e < ETOT) atomicAdd(&deg[ei[ETOT + e]], 1.0f);
}

__global__ void k_dis(float* __restrict__ dis) {
    int i = blockIdx.x * blockDim.x + threadIdx.x;
    if (i < NODES) {
        float d = dis[i];
        dis[i] = (d > 0.f) ? rsqrtf(fmaxf(d, 1.f)) : 0.f;
    }
}

__global__ void k_norm(const int* __restrict__ ei, const float* __restrict__ dis,
                       float* __restrict__ nrm) {
    int e = blockIdx.x * blockDim.x + threadIdx.x;
    if (e < ETOT) nrm[e] = -(dis[ei[e]] * dis[ei[ETOT + e]]);
}

// transpose w_hh (192x64, row-major) -> Wt (64x192, k-major)
__global__ void k_prep(const float* __restrict__ whe, const float* __restrict__ whd,
                       float* __restrict__ Wte, float* __restrict__ Wtd) {
    int i = blockIdx.x * blockDim.x + threadIdx.x;   // i = k*192 + g
    if (i < 192 * 64) {
        int k = i / 192, g = i - k * 192;
        Wte[i] = whe[g * 64 + k];
        Wtd[i] = whd[g * 64 + k];
    }
}

// ---------------- encoder step ----------------
// 1D grid of 1024 blocks (swizzled). Thread = one node, 8 output channels.
// Outer-product over k: 1 coalesced h load + 24 FMA (+1 for xn) per k.
__global__ __launch_bounds__(256) void k_enc(
    const float* __restrict__ pm,
    const float* __restrict__ w_ih, const float* __restrict__ Wt,
    const float* __restrict__ b_ih, const float* __restrict__ b_hh,
    const float* __restrict__ fc_w, const float* __restrict__ fc_b,
    const float* __restrict__ h_in, float* __restrict__ h_out,
    __hip_bfloat16* __restrict__ Hb, int t)
{
    int c, jg;
    swz(blockIdx.x, c, jg);
    const int node = c * 256 + threadIdx.x;
    if (node >= NODES) return;
    const int j0 = jg * 8;

    float accr[8], accz[8], accn[8];
    #pragma unroll
    for (int m = 0; m < 8; m++) {
        accr[m] = b_hh[j0 + m];
        accz[m] = b_hh[64 + j0 + m];
        accn[m] = b_hh[128 + j0 + m];
    }
    float axn = 0.f;
    const float* hp = h_in + node;
    #pragma unroll 4
    for (int k = 0; k < HID; k++) {
        const float hk = hp[(size_t)k * NODES];
        const float* w = Wt + k * 192 + j0;
        #pragma unroll
        for (int m = 0; m < 8; m++) {
            accr[m] = fmaf(w[m],       hk, accr[m]);
            accz[m] = fmaf(w[64 + m],  hk, accz[m]);
            accn[m] = fmaf(w[128 + m], hk, accn[m]);
        }
        axn = fmaf(fc_w[k], hk, axn);
    }
    const float xn = (t > 0) ? (axn + fc_b[0]) : 0.f;

    const int b = node / NN, n = node - b * NN;
    const float pmv = pm[(b * TH + t) * NN + n];

    #pragma unroll
    for (int m = 0; m < 8; m++) {
        const int j = j0 + m;
        float gr = b_ih[j]       + w_ih[2 * j] * xn         + w_ih[2 * j + 1] * pmv;
        float gz = b_ih[64 + j]  + w_ih[2 * (64 + j)] * xn  + w_ih[2 * (64 + j) + 1] * pmv;
        float gn = b_ih[128 + j] + w_ih[2 * (128 + j)] * xn + w_ih[2 * (128 + j) + 1] * pmv;
        float r   = sigmoidf_(gr + accr[m]);
        float z   = sigmoidf_(gz + accz[m]);
        float nn_ = tanhf_(gn + r * accn[m]);
        float hold = h_in[(size_t)j * NODES + node];
        float hv = (1.f - z) * nn_ + z * hold;
        h_out[(size_t)j * NODES + node] = hv;
        Hb[(size_t)node * (TH * HID) + t * HID + j] = __float2bfloat16(hv);
    }
}

// after encoder: xn0 = fc(h_final); y1 for decoder t=0; zero tx
__global__ __launch_bounds__(256) void k_fc(
    const float* __restrict__ h_in, const float* __restrict__ fc_w,
    const float* __restrict__ fc_b, const float* __restrict__ feat,
    const float* __restrict__ cw1, float* __restrict__ xn_buf,
    float* __restrict__ y1, float* __restrict__ tx)
{
    const int node = blockIdx.x * 256 + threadIdx.x;
    if (node >= NODES) return;
    float acc = fc_b[0];
    for (int k = 0; k < HID; k++) acc += fc_w[k] * h_in[(size_t)k * NODES + node];
    xn_buf[node] = acc;
    tx[node] = 0.f;
    const int b = node / NN, n = node - b * NN;
    const float* fp = feat + ((size_t)(b * TT + TH) * NN + n) * NF;
    float yy = acc * cw1[0];
    #pragma unroll
    for (int c = 0; c < NF; c++) yy += fp[c] * cw1[1 + c];
    y1[node] = yy;
}

// ---------------- decoder kernels ----------------
__global__ void k_scatter(const int* __restrict__ ei, const float* __restrict__ nrm,
                          const float* __restrict__ y1, float* __restrict__ tx)
{
    int e = blockIdx.x * blockDim.x + threadIdx.x;
    if (e < ETOT) {
        float v = nrm[e] * y1[ei[e]];
        atomicAdd(&tx[ei[ETOT + e]], v);
    }
}

__global__ __launch_bounds__(256) void k_dgru(
    const float* __restrict__ feat,
    const float* __restrict__ w_ih, const float* __restrict__ Wt,
    const float* __restrict__ b_ih, const float* __restrict__ b_hh,
    const float* __restrict__ w0, const float* __restrict__ cb,
    const float* __restrict__ xn_buf, const float* __restrict__ tx,
    const float* __restrict__ h_in, float* __restrict__ h_out,
    float* __restrict__ h_nm, int t)
{
    int c, jg;
    swz(blockIdx.x, c, jg);
    const int node = c * 256 + threadIdx.x;
    if (node >= NODES) return;
    const int j0 = jg * 8;

    float accr[8], accz[8], accn[8];
    #pragma unroll
    for (int m = 0; m < 8; m++) {
        accr[m] = b_hh[j0 + m];
        accz[m] = b_hh[64 + j0 + m];
        accn[m] = b_hh[128 + j0 + m];
    }
    const float* hp = h_in + node;
    #pragma unroll 4
    for (int k = 0; k < HID; k++) {
        const float hk = hp[(size_t)k * NODES];
        const float* w = Wt + k * 192 + j0;
        #pragma unroll
        for (int m = 0; m < 8; m++) {
            accr[m] = fmaf(w[m],       hk, accr[m]);
            accz[m] = fmaf(w[64 + m],  hk, accz[m]);
            accn[m] = fmaf(w[128 + m], hk, accn[m]);
        }
    }

    const int b = node / NN, n = node - b * NN;
    const float xnv = xn_buf[node];
    float f[NF];
    const float* fp = feat + ((size_t)(b * TT + TH + t) * NN + n) * NF;
    #pragma unroll
    for (int q = 0; q < NF; q++) f[q] = fp[q];

    float xw0 = xnv * w0[0];
    #pragma unroll
    for (int q = 0; q < NF; q++) xw0 = fmaf(f[q], w0[1 + q], xw0);
    const float xg = sigmoidf_(xw0 + tx[node] + cb[0]);

    #pragma unroll
    for (int m = 0; m < 8; m++) {
        const int j = j0 + m;
        const float* ir  = w_ih + j * 10;
        const float* iz  = w_ih + (64 + j) * 10;
        const float* in_ = w_ih + (128 + j) * 10;
        float gr = b_ih[j]       + ir[0] * xnv;
        float gz = b_ih[64 + j]  + iz[0] * xnv;
        float gn = b_ih[128 + j] + in_[0] * xnv;
        #pragma unroll
        for (int q = 0; q < NF; q++) {
            gr = fmaf(ir[1 + q],  f[q], gr);
            gz = fmaf(iz[1 + q],  f[q], gz);
            gn = fmaf(in_[1 + q], f[q], gn);
        }
        gr = fmaf(ir[9],  xg, gr);
        gz = fmaf(iz[9],  xg, gz);
        gn = fmaf(in_[9], xg, gn);

        float r   = sigmoidf_(gr + accr[m]);
        float z   = sigmoidf_(gz + accz[m]);
        float nn_ = tanhf_(gn + r * accn[m]);
        float hold = h_in[(size_t)j * NODES + node];
        float hv = (1.f - z) * nn_ + z * hold;
        h_out[(size_t)j * NODES + node] = hv;
        h_nm[(size_t)node * HID + j] = hv;
    }
}

// attention + out-projection + (y1, tx) prep for next step. Wave per node.
// Vectorized: one dwordx4 load covers 8 timesteps x 8 channels per lane.
// lane -> tloc = lane>>3 (within round), d0 = (lane&7)*8.
__global__ __launch_bounds__(256) void k_attn(
    const __hip_bfloat16* __restrict__ Hb, const float* __restrict__ h_nm,
    const float* __restrict__ out_w, const float* __restrict__ out_b,
    const float* __restrict__ feat, const float* __restrict__ cw1,
    float* __restrict__ xn_buf, float* __restrict__ y1, float* __restrict__ tx,
    float* __restrict__ out, int t)
{
    const int wid  = threadIdx.x >> 6;
    const int lane = threadIdx.x & 63;
    const int node = blockIdx.x * 4 + wid;
    if (node >= NODES) return;
    const int d0 = (lane & 7) * 8;     // channel block this lane owns

    // h vector: one coalesced load, then gather own channel block via shuffles
    const float hj = h_nm[(size_t)node * HID + lane];
    float hval[8];
    #pragma unroll
    for (int q = 0; q < 8; q++) hval[q] = __shfl(hj, d0 + q, 64);

    // H rows: 3 rounds x (64 lanes x 16B) = 24 timesteps
    const uint4* Hrow = (const uint4*)(Hb + (size_t)node * (TH * HID));
    float Hf[3][8];
    float er[3];
    #pragma unroll
    for (int R = 0; R < 3; R++) {
        const uint4 v = Hrow[R * 64 + lane];
        const uint32_t u0 = v.x, u1 = v.y, u2 = v.z, u3 = v.w;
        Hf[R][0] = __uint_as_float(u0 << 16);
        Hf[R][1] = __uint_as_float(u0 & 0xffff0000u);
        Hf[R][2] = __uint_as_float(u1 << 16);
        Hf[R][3] = __uint_as_float(u1 & 0xffff0000u);
        Hf[R][4] = __uint_as_float(u2 << 16);
        Hf[R][5] = __uint_as_float(u2 & 0xffff0000u);
        Hf[R][6] = __uint_as_float(u3 << 16);
        Hf[R][7] = __uint_as_float(u3 & 0xffff0000u);
        float part = 0.f;
        #pragma unroll
        for (int q = 0; q < 8; q++) part = fmaf(Hf[R][q], hval[q], part);
        part += __shfl_xor(part, 1, 64);
        part += __shfl_xor(part, 2, 64);
        part += __shfl_xor(part, 4, 64);
        er[R] = part;   // e[8R + (lane>>3)], uniform within 8-lane group
    }

    // softmax over 24 t's distributed across 8 groups x 3 rounds
    float m = fmaxf(fmaxf(er[0], er[1]), er[2]);
    m = fmaxf(m, __shfl_xor(m, 8, 64));
    m = fmaxf(m, __shfl_xor(m, 16, 64));
    m = fmaxf(m, __shfl_xor(m, 32, 64));

    float w0_ = __expf(er[0] - m);
    float w1_ = __expf(er[1] - m);
    float w2_ = __expf(er[2] - m);
    float s = w0_ + w1_ + w2_;
    s += __shfl_xor(s, 8, 64);
    s += __shfl_xor(s, 16, 64);
    s += __shfl_xor(s, 32, 64);
    const float rs = 1.f / s;

    // weighted sum over t for this lane's channel block
    float aq[8];
    #pragma unroll
    for (int q = 0; q < 8; q++) {
        float a = w0_ * Hf[0][q];
        a = fmaf(w1_, Hf[1][q], a);
        a = fmaf(w2_, Hf[2][q], a);
        a += __shfl_xor(a, 8, 64);
        a += __shfl_xor(a, 16, 64);
        a += __shfl_xor(a, 32, 64);
        aq[q] = a * rs;
    }

    // out projection: concat(a, h) . out_w
    float part = 0.f;
    #pragma unroll
    for (int q = 0; q < 8; q++) {
        part = fmaf(out_w[d0 + q],       aq[q],   part);
        part = fmaf(out_w[HID + d0 + q], hval[q], part);
    }
    part += __shfl_xor(part, 1, 64);
    part += __shfl_xor(part, 2, 64);
    part += __shfl_xor(part, 4, 64);
    const float xnew = part + out_b[0];

    if (lane == 0) {
        const int b = node / NN, n = node - b * NN;
        out[(b * TF + t) * NN + n] = xnew;
        xn_buf[node] = xnew;
        tx[node] = 0.f;
        if (t + 1 < TF) {
            const float* fp = feat + ((size_t)(b * TT + TH + t + 1) * NN + n) * NF;
            float yy = xnew * cw1[0];
            #pragma unroll
            for (int c = 0; c < NF; c++) yy += fp[c] * cw1[1 + c];
            y1[node] = yy;
        }
    }
}

// ---------------- host launch ----------------
extern "C" void kernel_launch(void* const* d_in, const int* in_sizes, int n_in,
                              void* d_out, int out_size, void* d_ws, size_t ws_size,
                              hipStream_t stream)
{
    const float* pm     = (const float*)d_in[0];
    const float* feat   = (const float*)d_in[1];
    const int*   ei     = (const int*)d_in[2];
    const float* w_ih_e = (const float*)d_in[3];
    const float* w_hh_e = (const float*)d_in[4];
    const float* b_ih_e = (const float*)d_in[5];
    const float* b_hh_e = (const float*)d_in[6];
    const float* fc_w   = (const float*)d_in[7];
    const float* fc_b   = (const float*)d_in[8];
    const float* cw0    = (const float*)d_in[9];
    const float* cw1    = (const float*)d_in[10];
    const float* cb     = (const float*)d_in[11];
    const float* w_ih_d = (const float*)d_in[12];
    const float* w_hh_d = (const float*)d_in[13];
    const float* b_ih_d = (const float*)d_in[14];
    const float* b_hh_d = (const float*)d_in[15];
    const float* out_w  = (const float*)d_in[16];
    const float* out_b  = (const float*)d_in[17];
    float* out = (float*)d_out;

    char* ws = (char*)d_ws;
    size_t off = 0;
    auto alloc = [&](size_t bytes) -> void* {
        void* p = ws + off;
        off += (bytes + 255) & ~(size_t)255;
        return p;
    };
    float* hA   = (float*)alloc(sizeof(float) * HID * NODES);
    float* hB   = (float*)alloc(sizeof(float) * HID * NODES);
    float* h_nm = (float*)alloc(sizeof(float) * HID * NODES);
    __hip_bfloat16* Hb = (__hip_bfloat16*)alloc(sizeof(__hip_bfloat16) * (size_t)NODES * TH * HID);
    float* xn   = (float*)alloc(sizeof(float) * NODES);
    float* dis  = (float*)alloc(sizeof(float) * NODES);
    float* y1   = (float*)alloc(sizeof(float) * NODES);
    float* tx   = (float*)alloc(sizeof(float) * NODES);
    float* nrm  = (float*)alloc(sizeof(float) * ETOT);
    float* WtE  = (float*)alloc(sizeof(float) * 192 * 64);
    float* WtD  = (float*)alloc(sizeof(float) * 192 * 64);
    if (off > ws_size) return;  // visible failure instead of corruption

    // setup: zero h0, degree -> dis -> edge norms, weight transposes
    k_init<<<(HID * NODES + 255) / 256, 256, 0, stream>>>(hA, dis);
    k_deg<<<(ETOT + 255) / 256, 256, 0, stream>>>(ei, dis);
    k_dis<<<(NODES + 255) / 256, 256, 0, stream>>>(dis);
    k_norm<<<(ETOT + 255) / 256, 256, 0, stream>>>(ei, dis, nrm);
    k_prep<<<(192 * 64 + 255) / 256, 256, 0, stream>>>(w_hh_e, w_hh_d, WtE, WtD);

    const int gGRU = NCH * 8;   // 1024 swizzled blocks

    // encoder: ping-pong hA/hB; 24 steps ends back in hA
    for (int t = 0; t < TH; t++) {
        const float* hin = (t & 1) ? hB : hA;
        float* hout      = (t & 1) ? hA : hB;
        k_enc<<<gGRU, 256, 0, stream>>>(pm, w_ih_e, WtE, b_ih_e, b_hh_e,
                                        fc_w, fc_b, hin, hout, Hb, t);
    }
    k_fc<<<NODES / 256, 256, 0, stream>>>(hA, fc_w, fc_b, feat, cw1, xn, y1, tx);

    // decoder
    for (int t = 0; t < TF; t++) {
        const float* hin = (t & 1) ? hB : hA;
        float* hout      = (t & 1) ? hA : hB;
        k_scatter<<<(ETOT + 255) / 256, 256, 0, stream>>>(ei, nrm, y1, tx);
        k_dgru<<<gGRU, 256, 0, stream>>>(feat, w_ih_d, WtD, b_ih_d, b_hh_d,
                                         cw0, cb, xn, tx, hin, hout, h_nm, t);
        k_attn<<<NODES / 4, 256, 0, stream>>>(Hb, h_nm, out_w, out_b, feat, cw1,
                                              xn, y1, tx, out, t);
    }
}

// Round 4
// 1853.912 us; speedup vs baseline: 2.6954x; 1.5402x over previous
//
#include <hip/hip_runtime.h>
#include <hip/hip_bf16.h>
#include <cstddef>
#include <cstdint>

// Problem constants (match reference)
constexpr int NB    = 16;       // batch
constexpr int NN    = 2000;     // nodes per batch
constexpr int TH    = 24;       // T_HIST
constexpr int TF    = 24;       // T_FCST
constexpr int HID   = 64;
constexpr int NF    = 8;        // features
constexpr int NODES = NB * NN;      // 32000
constexpr int ETOT  = NODES * 32;   // 1,024,000 edges
constexpr int TT    = TH + TF;      // 48
constexpr int NCH   = 128;          // node chunks of 256 (padded: 125 real)

__device__ __forceinline__ float sigmoidf_(float x) { return 1.f / (1.f + __expf(-x)); }
__device__ __forceinline__ float tanhf_(float x) {
    float e = __expf(2.f * x);
    return 1.f - 2.f / (e + 1.f);   // safe at +/-inf
}

// Decode swizzled 1D block id -> (chunk c, jgroup jg) such that all 8 jgroups
// of a chunk share (id % 8)  => same XCD under round-robin dispatch.
__device__ __forceinline__ void swz(int id, int& c, int& jg) {
    int low = id & 7;       // xcd
    int q   = id >> 3;      // [0,128)
    jg      = q >> 4;       // [0,8)
    int chi = q & 15;       // [0,16)
    c       = chi * 8 + low;
}

// ---------------- setup kernels ----------------
__global__ void k_init(float* __restrict__ hA, float* __restrict__ dis) {
    int i = blockIdx.x * blockDim.x + threadIdx.x;
    if (i < HID * NODES) hA[i] = 0.f;
    if (i < NODES) dis[i] = 0.f;
}

__global__ void k_deg(const int* __restrict__ ei, float* __restrict__ deg) {
    int e = blockIdx.x * blockDim.x + threadIdx.x;
    if (e < ETOT) atomicAdd(&deg[ei[ETOT + e]], 1.0f);
}

// single block of 256: exclusive prefix sum of (int)degf -> row0[NODES+1], zero cnt
__global__ __launch_bounds__(256) void k_scan(const float* __restrict__ degf,
                                              int* __restrict__ row0,
                                              int* __restrict__ cnt)
{
    __shared__ int part[256];
    const int tid = threadIdx.x;
    const int per = NODES / 256;   // 125
    const int base = tid * per;
    int s = 0;
    for (int i = 0; i < per; i++) s += (int)degf[base + i];
    part[tid] = s;
    __syncthreads();
    // Hillis-Steele inclusive scan over 256 partials
    for (int off = 1; off < 256; off <<= 1) {
        int v = (tid >= off) ? part[tid - off] : 0;
        __syncthreads();
        part[tid] += v;
        __syncthreads();
    }
    int run = (tid == 0) ? 0 : part[tid - 1];
    for (int i = 0; i < per; i++) {
        row0[base + i] = run;
        cnt[base + i]  = 0;
        run += (int)degf[base + i];
    }
    if (tid == 255) row0[NODES] = run;
}

__global__ void k_dis(float* __restrict__ dis) {
    int i = blockIdx.x * blockDim.x + threadIdx.x;
    if (i < NODES) {
        float d = dis[i];
        dis[i] = (d > 0.f) ? rsqrtf(fmaxf(d, 1.f)) : 0.f;
    }
}

__global__ void k_norm(const int* __restrict__ ei, const float* __restrict__ dis,
                       float* __restrict__ nrm) {
    int e = blockIdx.x * blockDim.x + threadIdx.x;
    if (e < ETOT) nrm[e] = -(dis[ei[e]] * dis[ei[ETOT + e]]);
}

// build dst-CSR: one-time atomics
__global__ void k_fill(const int* __restrict__ ei, const float* __restrict__ nrm,
                       const int* __restrict__ row0, int* __restrict__ cnt,
                       int* __restrict__ csrc, float* __restrict__ cnrm)
{
    int e = blockIdx.x * blockDim.x + threadIdx.x;
    if (e < ETOT) {
        int d = ei[ETOT + e];
        int p = atomicAdd(&cnt[d], 1);
        int idx = row0[d] + p;
        csrc[idx] = ei[e];
        cnrm[idx] = nrm[e];
    }
}

// transpose w_hh (192x64, row-major) -> Wt (64x192, k-major)
__global__ void k_prep(const float* __restrict__ whe, const float* __restrict__ whd,
                       float* __restrict__ Wte, float* __restrict__ Wtd) {
    int i = blockIdx.x * blockDim.x + threadIdx.x;   // i = k*192 + g
    if (i < 192 * 64) {
        int k = i / 192, g = i - k * 192;
        Wte[i] = whe[g * 64 + k];
        Wtd[i] = whd[g * 64 + k];
    }
}

// ---------------- encoder step ----------------
// 1D grid of 1024 blocks (swizzled). Thread = one node, 8 output channels.
// Outer-product over k: 1 coalesced h load + 24 FMA (+1 for xn) per k.
__global__ __launch_bounds__(256) void k_enc(
    const float* __restrict__ pm,
    const float* __restrict__ w_ih, const float* __restrict__ Wt,
    const float* __restrict__ b_ih, const float* __restrict__ b_hh,
    const float* __restrict__ fc_w, const float* __restrict__ fc_b,
    const float* __restrict__ h_in, float* __restrict__ h_out,
    __hip_bfloat16* __restrict__ Hb, int t)
{
    int c, jg;
    swz(blockIdx.x, c, jg);
    const int node = c * 256 + threadIdx.x;
    if (node >= NODES) return;
    const int j0 = jg * 8;

    float accr[8], accz[8], accn[8];
    #pragma unroll
    for (int m = 0; m < 8; m++) {
        accr[m] = b_hh[j0 + m];
        accz[m] = b_hh[64 + j0 + m];
        accn[m] = b_hh[128 + j0 + m];
    }
    float axn = 0.f;
    const float* hp = h_in + node;
    #pragma unroll 4
    for (int k = 0; k < HID; k++) {
        const float hk = hp[(size_t)k * NODES];
        const float* w = Wt + k * 192 + j0;
        #pragma unroll
        for (int m = 0; m < 8; m++) {
            accr[m] = fmaf(w[m],       hk, accr[m]);
            accz[m] = fmaf(w[64 + m],  hk, accz[m]);
            accn[m] = fmaf(w[128 + m], hk, accn[m]);
        }
        axn = fmaf(fc_w[k], hk, axn);
    }
    const float xn = (t > 0) ? (axn + fc_b[0]) : 0.f;

    const int b = node / NN, n = node - b * NN;
    const float pmv = pm[(b * TH + t) * NN + n];

    #pragma unroll
    for (int m = 0; m < 8; m++) {
        const int j = j0 + m;
        float gr = b_ih[j]       + w_ih[2 * j] * xn         + w_ih[2 * j + 1] * pmv;
        float gz = b_ih[64 + j]  + w_ih[2 * (64 + j)] * xn  + w_ih[2 * (64 + j) + 1] * pmv;
        float gn = b_ih[128 + j] + w_ih[2 * (128 + j)] * xn + w_ih[2 * (128 + j) + 1] * pmv;
        float r   = sigmoidf_(gr + accr[m]);
        float z   = sigmoidf_(gz + accz[m]);
        float nn_ = tanhf_(gn + r * accn[m]);
        float hold = h_in[(size_t)j * NODES + node];
        float hv = (1.f - z) * nn_ + z * hold;
        h_out[(size_t)j * NODES + node] = hv;
        Hb[(size_t)node * (TH * HID) + t * HID + j] = __float2bfloat16(hv);
    }
}

// after encoder: xn0 = fc(h_final); y1 for decoder t=0
__global__ __launch_bounds__(256) void k_fc(
    const float* __restrict__ h_in, const float* __restrict__ fc_w,
    const float* __restrict__ fc_b, const float* __restrict__ feat,
    const float* __restrict__ cw1, float* __restrict__ xn_buf,
    float* __restrict__ y1)
{
    const int node = blockIdx.x * 256 + threadIdx.x;
    if (node >= NODES) return;
    float acc = fc_b[0];
    for (int k = 0; k < HID; k++) acc += fc_w[k] * h_in[(size_t)k * NODES + node];
    xn_buf[node] = acc;
    const int b = node / NN, n = node - b * NN;
    const float* fp = feat + ((size_t)(b * TT + TH) * NN + n) * NF;
    float yy = acc * cw1[0];
    #pragma unroll
    for (int c = 0; c < NF; c++) yy += fp[c] * cw1[1 + c];
    y1[node] = yy;
}

// ---------------- decoder kernels ----------------
// CSR gather: 4 lanes per node, interleaved edge walk, shuffle-reduce.
__global__ __launch_bounds__(256) void k_gather(
    const int* __restrict__ row0, const int* __restrict__ csrc,
    const float* __restrict__ cnrm, const float* __restrict__ y1,
    float* __restrict__ tx)
{
    const int tid  = blockIdx.x * 256 + threadIdx.x;
    const int node = tid >> 2;
    const int q    = tid & 3;
    if (node >= NODES) return;
    const int beg = row0[node], end = row0[node + 1];
    float acc = 0.f;
    for (int i = beg + q; i < end; i += 4)
        acc = fmaf(cnrm[i], y1[csrc[i]], acc);
    acc += __shfl_xor(acc, 1, 64);
    acc += __shfl_xor(acc, 2, 64);
    if (q == 0) tx[node] = acc;
}

__global__ __launch_bounds__(256) void k_dgru(
    const float* __restrict__ feat,
    const float* __restrict__ w_ih, const float* __restrict__ Wt,
    const float* __restrict__ b_ih, const float* __restrict__ b_hh,
    const float* __restrict__ w0, const float* __restrict__ cb,
    const float* __restrict__ xn_buf, const float* __restrict__ tx,
    const float* __restrict__ h_in, float* __restrict__ h_out,
    float* __restrict__ h_nm, int t)
{
    int c, jg;
    swz(blockIdx.x, c, jg);
    const int node = c * 256 + threadIdx.x;
    if (node >= NODES) return;
    const int j0 = jg * 8;

    float accr[8], accz[8], accn[8];
    #pragma unroll
    for (int m = 0; m < 8; m++) {
        accr[m] = b_hh[j0 + m];
        accz[m] = b_hh[64 + j0 + m];
        accn[m] = b_hh[128 + j0 + m];
    }
    const float* hp = h_in + node;
    #pragma unroll 4
    for (int k = 0; k < HID; k++) {
        const float hk = hp[(size_t)k * NODES];
        const float* w = Wt + k * 192 + j0;
        #pragma unroll
        for (int m = 0; m < 8; m++) {
            accr[m] = fmaf(w[m],       hk, accr[m]);
            accz[m] = fmaf(w[64 + m],  hk, accz[m]);
            accn[m] = fmaf(w[128 + m], hk, accn[m]);
        }
    }

    const int b = node / NN, n = node - b * NN;
    const float xnv = xn_buf[node];
    float f[NF];
    const float* fp = feat + ((size_t)(b * TT + TH + t) * NN + n) * NF;
    #pragma unroll
    for (int q = 0; q < NF; q++) f[q] = fp[q];

    float xw0 = xnv * w0[0];
    #pragma unroll
    for (int q = 0; q < NF; q++) xw0 = fmaf(f[q], w0[1 + q], xw0);
    const float xg = sigmoidf_(xw0 + tx[node] + cb[0]);

    #pragma unroll
    for (int m = 0; m < 8; m++) {
        const int j = j0 + m;
        const float* ir  = w_ih + j * 10;
        const float* iz  = w_ih + (64 + j) * 10;
        const float* in_ = w_ih + (128 + j) * 10;
        float gr = b_ih[j]       + ir[0] * xnv;
        float gz = b_ih[64 + j]  + iz[0] * xnv;
        float gn = b_ih[128 + j] + in_[0] * xnv;
        #pragma unroll
        for (int q = 0; q < NF; q++) {
            gr = fmaf(ir[1 + q],  f[q], gr);
            gz = fmaf(iz[1 + q],  f[q], gz);
            gn = fmaf(in_[1 + q], f[q], gn);
        }
        gr = fmaf(ir[9],  xg, gr);
        gz = fmaf(iz[9],  xg, gz);
        gn = fmaf(in_[9], xg, gn);

        float r   = sigmoidf_(gr + accr[m]);
        float z   = sigmoidf_(gz + accz[m]);
        float nn_ = tanhf_(gn + r * accn[m]);
        float hold = h_in[(size_t)j * NODES + node];
        float hv = (1.f - z) * nn_ + z * hold;
        h_out[(size_t)j * NODES + node] = hv;
        h_nm[(size_t)node * HID + j] = hv;
    }
}

// attention + out-projection + y1 prep for next step. Wave per node.
// Vectorized: one dwordx4 load covers 8 timesteps x 8 channels per lane.
__global__ __launch_bounds__(256) void k_attn(
    const __hip_bfloat16* __restrict__ Hb, const float* __restrict__ h_nm,
    const float* __restrict__ out_w, const float* __restrict__ out_b,
    const float* __restrict__ feat, const float* __restrict__ cw1,
    float* __restrict__ xn_buf, float* __restrict__ y1,
    float* __restrict__ out, int t)
{
    const int wid  = threadIdx.x >> 6;
    const int lane = threadIdx.x & 63;
    const int node = blockIdx.x * 4 + wid;
    if (node >= NODES) return;
    const int d0 = (lane & 7) * 8;     // channel block this lane owns

    // h vector: one coalesced load, then gather own channel block via shuffles
    const float hj = h_nm[(size_t)node * HID + lane];
    float hval[8];
    #pragma unroll
    for (int q = 0; q < 8; q++) hval[q] = __shfl(hj, d0 + q, 64);

    // H rows: 3 rounds x (64 lanes x 16B) = 24 timesteps
    const uint4* Hrow = (const uint4*)(Hb + (size_t)node * (TH * HID));
    float Hf[3][8];
    float er[3];
    #pragma unroll
    for (int R = 0; R < 3; R++) {
        const uint4 v = Hrow[R * 64 + lane];
        const uint32_t u0 = v.x, u1 = v.y, u2 = v.z, u3 = v.w;
        Hf[R][0] = __uint_as_float(u0 << 16);
        Hf[R][1] = __uint_as_float(u0 & 0xffff0000u);
        Hf[R][2] = __uint_as_float(u1 << 16);
        Hf[R][3] = __uint_as_float(u1 & 0xffff0000u);
        Hf[R][4] = __uint_as_float(u2 << 16);
        Hf[R][5] = __uint_as_float(u2 & 0xffff0000u);
        Hf[R][6] = __uint_as_float(u3 << 16);
        Hf[R][7] = __uint_as_float(u3 & 0xffff0000u);
        float part = 0.f;
        #pragma unroll
        for (int q = 0; q < 8; q++) part = fmaf(Hf[R][q], hval[q], part);
        part += __shfl_xor(part, 1, 64);
        part += __shfl_xor(part, 2, 64);
        part += __shfl_xor(part, 4, 64);
        er[R] = part;   // e[8R + (lane>>3)], uniform within 8-lane group
    }

    // softmax over 24 t's distributed across 8 groups x 3 rounds
    float m = fmaxf(fmaxf(er[0], er[1]), er[2]);
    m = fmaxf(m, __shfl_xor(m, 8, 64));
    m = fmaxf(m, __shfl_xor(m, 16, 64));
    m = fmaxf(m, __shfl_xor(m, 32, 64));

    float w0_ = __expf(er[0] - m);
    float w1_ = __expf(er[1] - m);
    float w2_ = __expf(er[2] - m);
    float s = w0_ + w1_ + w2_;
    s += __shfl_xor(s, 8, 64);
    s += __shfl_xor(s, 16, 64);
    s += __shfl_xor(s, 32, 64);
    const float rs = 1.f / s;

    // weighted sum over t for this lane's channel block
    float aq[8];
    #pragma unroll
    for (int q = 0; q < 8; q++) {
        float a = w0_ * Hf[0][q];
        a = fmaf(w1_, Hf[1][q], a);
        a = fmaf(w2_, Hf[2][q], a);
        a += __shfl_xor(a, 8, 64);
        a += __shfl_xor(a, 16, 64);
        a += __shfl_xor(a, 32, 64);
        aq[q] = a * rs;
    }

    // out projection: concat(a, h) . out_w
    float part = 0.f;
    #pragma unroll
    for (int q = 0; q < 8; q++) {
        part = fmaf(out_w[d0 + q],       aq[q],   part);
        part = fmaf(out_w[HID + d0 + q], hval[q], part);
    }
    part += __shfl_xor(part, 1, 64);
    part += __shfl_xor(part, 2, 64);
    part += __shfl_xor(part, 4, 64);
    const float xnew = part + out_b[0];

    if (lane == 0) {
        const int b = node / NN, n = node - b * NN;
        out[(b * TF + t) * NN + n] = xnew;
        xn_buf[node] = xnew;
        if (t + 1 < TF) {
            const float* fp = feat + ((size_t)(b * TT + TH + t + 1) * NN + n) * NF;
            float yy = xnew * cw1[0];
            #pragma unroll
            for (int c = 0; c < NF; c++) yy += fp[c] * cw1[1 + c];
            y1[node] = yy;
        }
    }
}

// ---------------- host launch ----------------
extern "C" void kernel_launch(void* const* d_in, const int* in_sizes, int n_in,
                              void* d_out, int out_size, void* d_ws, size_t ws_size,
                              hipStream_t stream)
{
    const float* pm     = (const float*)d_in[0];
    const float* feat   = (const float*)d_in[1];
    const int*   ei     = (const int*)d_in[2];
    const float* w_ih_e = (const float*)d_in[3];
    const float* w_hh_e = (const float*)d_in[4];
    const float* b_ih_e = (const float*)d_in[5];
    const float* b_hh_e = (const float*)d_in[6];
    const float* fc_w   = (const float*)d_in[7];
    const float* fc_b   = (const float*)d_in[8];
    const float* cw0    = (const float*)d_in[9];
    const float* cw1    = (const float*)d_in[10];
    const float* cb     = (const float*)d_in[11];
    const float* w_ih_d = (const float*)d_in[12];
    const float* w_hh_d = (const float*)d_in[13];
    const float* b_ih_d = (const float*)d_in[14];
    const float* b_hh_d = (const float*)d_in[15];
    const float* out_w  = (const float*)d_in[16];
    const float* out_b  = (const float*)d_in[17];
    float* out = (float*)d_out;

    char* ws = (char*)d_ws;
    size_t off = 0;
    auto alloc = [&](size_t bytes) -> void* {
        void* p = ws + off;
        off += (bytes + 255) & ~(size_t)255;
        return p;
    };
    float* hA   = (float*)alloc(sizeof(float) * HID * NODES);
    float* hB   = (float*)alloc(sizeof(float) * HID * NODES);
    float* h_nm = (float*)alloc(sizeof(float) * HID * NODES);
    __hip_bfloat16* Hb = (__hip_bfloat16*)alloc(sizeof(__hip_bfloat16) * (size_t)NODES * TH * HID);
    float* xn   = (float*)alloc(sizeof(float) * NODES);
    float* dis  = (float*)alloc(sizeof(float) * NODES);
    float* y1   = (float*)alloc(sizeof(float) * NODES);
    float* tx   = (float*)alloc(sizeof(float) * NODES);
    float* nrm  = (float*)alloc(sizeof(float) * ETOT);
    float* WtE  = (float*)alloc(sizeof(float) * 192 * 64);
    float* WtD  = (float*)alloc(sizeof(float) * 192 * 64);
    int*   row0 = (int*)alloc(sizeof(int) * (NODES + 1));
    int*   cnt  = (int*)alloc(sizeof(int) * NODES);
    int*   csrc = (int*)alloc(sizeof(int) * ETOT);
    float* cnrm = (float*)alloc(sizeof(float) * ETOT);
    if (off > ws_size) return;  // visible failure instead of corruption

    // setup: zero h0+deg, degree -> scan -> dis -> edge norms -> CSR, transposes
    k_init<<<(HID * NODES + 255) / 256, 256, 0, stream>>>(hA, dis);
    k_deg<<<(ETOT + 255) / 256, 256, 0, stream>>>(ei, dis);
    k_scan<<<1, 256, 0, stream>>>(dis, row0, cnt);
    k_dis<<<(NODES + 255) / 256, 256, 0, stream>>>(dis);
    k_norm<<<(ETOT + 255) / 256, 256, 0, stream>>>(ei, dis, nrm);
    k_fill<<<(ETOT + 255) / 256, 256, 0, stream>>>(ei, nrm, row0, cnt, csrc, cnrm);
    k_prep<<<(192 * 64 + 255) / 256, 256, 0, stream>>>(w_hh_e, w_hh_d, WtE, WtD);

    const int gGRU = NCH * 8;   // 1024 swizzled blocks

    // encoder: ping-pong hA/hB; 24 steps ends back in hA
    for (int t = 0; t < TH; t++) {
        const float* hin = (t & 1) ? hB : hA;
        float* hout      = (t & 1) ? hA : hB;
        k_enc<<<gGRU, 256, 0, stream>>>(pm, w_ih_e, WtE, b_ih_e, b_hh_e,
                                        fc_w, fc_b, hin, hout, Hb, t);
    }
    k_fc<<<NODES / 256, 256, 0, stream>>>(hA, fc_w, fc_b, feat, cw1, xn, y1);

    // decoder
    for (int t = 0; t < TF; t++) {
        const float* hin = (t & 1) ? hB : hA;
        float* hout      = (t & 1) ? hA : hB;
        k_gather<<<(NODES * 4) / 256, 256, 0, stream>>>(row0, csrc, cnrm, y1, tx);
        k_dgru<<<gGRU, 256, 0, stream>>>(feat, w_ih_d, WtD, b_ih_d, b_hh_d,
                                         cw0, cb, xn, tx, hin, hout, h_nm, t);
        k_attn<<<NODES / 4, 256, 0, stream>>>(Hb, h_nm, out_w, out_b, feat, cw1,
                                              xn, y1, out, t);
    }
}

// Round 5
// 1788.967 us; speedup vs baseline: 2.7933x; 1.0363x over previous
//
#include <hip/hip_runtime.h>
#include <hip/hip_bf16.h>
#include <cstddef>
#include <cstdint>

// Problem constants (match reference)
constexpr int NB    = 16;       // batch
constexpr int NN    = 2000;     // nodes per batch
constexpr int TH    = 24;       // T_HIST
constexpr int TF    = 24;       // T_FCST
constexpr int HID   = 64;
constexpr int NF    = 8;        // features
constexpr int NODES = NB * NN;      // 32000
constexpr int ETOT  = NODES * 32;   // 1,024,000 edges
constexpr int TT    = TH + TF;      // 48
constexpr int NCH   = 128;          // node chunks of 256 (padded: 125 real)

__device__ __forceinline__ float sigmoidf_(float x) { return 1.f / (1.f + __expf(-x)); }
__device__ __forceinline__ float tanhf_(float x) {
    float e = __expf(2.f * x);
    return 1.f - 2.f / (e + 1.f);   // safe at +/-inf
}

__device__ __forceinline__ uint16_t f2bf(float x) {
    __hip_bfloat16 b = __float2bfloat16(x);
    uint16_t u; __builtin_memcpy(&u, &b, 2); return u;
}

// Decode swizzled 1D block id -> (chunk c, jgroup jg) such that all 8 jgroups
// of a chunk share (id % 8)  => same XCD under round-robin dispatch.
__device__ __forceinline__ void swz(int id, int& c, int& jg) {
    int low = id & 7;       // xcd
    int q   = id >> 3;      // [0,128)
    jg      = q >> 4;       // [0,8)
    int chi = q & 15;       // [0,16)
    c       = chi * 8 + low;
}

// ---------------- setup kernels ----------------
__global__ void k_init(float* __restrict__ hA, float* __restrict__ dis) {
    int i = blockIdx.x * blockDim.x + threadIdx.x;
    if (i < HID * NODES) hA[i] = 0.f;
    if (i < NODES) dis[i] = 0.f;
}

__global__ void k_deg(const int* __restrict__ ei, float* __restrict__ deg) {
    int e = blockIdx.x * blockDim.x + threadIdx.x;
    if (e < ETOT) atomicAdd(&deg[ei[ETOT + e]], 1.0f);
}

// single block of 256: exclusive prefix sum of (int)degf -> row0[NODES+1], zero cnt
__global__ __launch_bounds__(256) void k_scan(const float* __restrict__ degf,
                                              int* __restrict__ row0,
                                              int* __restrict__ cnt)
{
    __shared__ int part[256];
    const int tid = threadIdx.x;
    const int per = NODES / 256;   // 125
    const int base = tid * per;
    int s = 0;
    for (int i = 0; i < per; i++) s += (int)degf[base + i];
    part[tid] = s;
    __syncthreads();
    // Hillis-Steele inclusive scan over 256 partials
    for (int off = 1; off < 256; off <<= 1) {
        int v = (tid >= off) ? part[tid - off] : 0;
        __syncthreads();
        part[tid] += v;
        __syncthreads();
    }
    int run = (tid == 0) ? 0 : part[tid - 1];
    for (int i = 0; i < per; i++) {
        row0[base + i] = run;
        cnt[base + i]  = 0;
        run += (int)degf[base + i];
    }
    if (tid == 255) row0[NODES] = run;
}

__global__ void k_dis(float* __restrict__ dis) {
    int i = blockIdx.x * blockDim.x + threadIdx.x;
    if (i < NODES) {
        float d = dis[i];
        dis[i] = (d > 0.f) ? rsqrtf(fmaxf(d, 1.f)) : 0.f;
    }
}

__global__ void k_norm(const int* __restrict__ ei, const float* __restrict__ dis,
                       float* __restrict__ nrm) {
    int e = blockIdx.x * blockDim.x + threadIdx.x;
    if (e < ETOT) nrm[e] = -(dis[ei[e]] * dis[ei[ETOT + e]]);
}

// build dst-CSR: one-time atomics
__global__ void k_fill(const int* __restrict__ ei, const float* __restrict__ nrm,
                       const int* __restrict__ row0, int* __restrict__ cnt,
                       int* __restrict__ csrc, float* __restrict__ cnrm)
{
    int e = blockIdx.x * blockDim.x + threadIdx.x;
    if (e < ETOT) {
        int d = ei[ETOT + e];
        int p = atomicAdd(&cnt[d], 1);
        int idx = row0[d] + p;
        csrc[idx] = ei[e];
        cnrm[idx] = nrm[e];
    }
}

// transpose w_hh (192x64, row-major) -> Wt (64x192, k-major)
__global__ void k_prep(const float* __restrict__ whe, const float* __restrict__ whd,
                       float* __restrict__ Wte, float* __restrict__ Wtd) {
    int i = blockIdx.x * blockDim.x + threadIdx.x;   // i = k*192 + g
    if (i < 192 * 64) {
        int k = i / 192, g = i - k * 192;
        Wte[i] = whe[g * 64 + k];
        Wtd[i] = whd[g * 64 + k];
    }
}

// ---------------- encoder step ----------------
// h layout: float4-packed k-groups  h4[kq][node], kq = k/4, component = k%4.
// 1D grid of 1024 blocks (swizzled). Thread = one node, 8 output channels.
__global__ __launch_bounds__(256) void k_enc(
    const float* __restrict__ pm,
    const float* __restrict__ w_ih, const float* __restrict__ Wt,
    const float* __restrict__ b_ih, const float* __restrict__ b_hh,
    const float* __restrict__ fc_w, const float* __restrict__ fc_b,
    const float* __restrict__ h_in, float* __restrict__ h_out,
    __hip_bfloat16* __restrict__ Hb, int t)
{
    int c, jg;
    swz(blockIdx.x, c, jg);
    const int node = c * 256 + threadIdx.x;
    if (node >= NODES) return;
    const int j0 = jg * 8;

    float accr[8], accz[8], accn[8];
    #pragma unroll
    for (int m = 0; m < 8; m++) {
        accr[m] = b_hh[j0 + m];
        accz[m] = b_hh[64 + j0 + m];
        accn[m] = b_hh[128 + j0 + m];
    }
    float axn = 0.f;
    const float4* h4 = (const float4*)h_in;
    #pragma unroll 8
    for (int kq = 0; kq < 16; kq++) {
        const float4 hv = h4[(size_t)kq * NODES + node];
        const float hk[4] = {hv.x, hv.y, hv.z, hv.w};
        #pragma unroll
        for (int u = 0; u < 4; u++) {
            const int k = kq * 4 + u;
            const float* w = Wt + k * 192 + j0;
            #pragma unroll
            for (int m = 0; m < 8; m++) {
                accr[m] = fmaf(w[m],       hk[u], accr[m]);
                accz[m] = fmaf(w[64 + m],  hk[u], accz[m]);
                accn[m] = fmaf(w[128 + m], hk[u], accn[m]);
            }
            axn = fmaf(fc_w[k], hk[u], axn);
        }
    }
    const float xn = (t > 0) ? (axn + fc_b[0]) : 0.f;

    const int b = node / NN, n = node - b * NN;
    const float pmv = pm[(b * TH + t) * NN + n];

    const float4 hold0 = h4[(size_t)(2 * jg)     * NODES + node];
    const float4 hold1 = h4[(size_t)(2 * jg + 1) * NODES + node];
    const float holdv[8] = {hold0.x, hold0.y, hold0.z, hold0.w,
                            hold1.x, hold1.y, hold1.z, hold1.w};
    float hnew[8];
    #pragma unroll
    for (int m = 0; m < 8; m++) {
        const int j = j0 + m;
        float gr = b_ih[j]       + w_ih[2 * j] * xn         + w_ih[2 * j + 1] * pmv;
        float gz = b_ih[64 + j]  + w_ih[2 * (64 + j)] * xn  + w_ih[2 * (64 + j) + 1] * pmv;
        float gn = b_ih[128 + j] + w_ih[2 * (128 + j)] * xn + w_ih[2 * (128 + j) + 1] * pmv;
        float r   = sigmoidf_(gr + accr[m]);
        float z   = sigmoidf_(gz + accz[m]);
        float nn_ = tanhf_(gn + r * accn[m]);
        hnew[m] = (1.f - z) * nn_ + z * holdv[m];
    }
    float4* o4 = (float4*)h_out;
    o4[(size_t)(2 * jg)     * NODES + node] = make_float4(hnew[0], hnew[1], hnew[2], hnew[3]);
    o4[(size_t)(2 * jg + 1) * NODES + node] = make_float4(hnew[4], hnew[5], hnew[6], hnew[7]);

    const uint32_t p0 = (uint32_t)f2bf(hnew[0]) | ((uint32_t)f2bf(hnew[1]) << 16);
    const uint32_t p1 = (uint32_t)f2bf(hnew[2]) | ((uint32_t)f2bf(hnew[3]) << 16);
    const uint32_t p2 = (uint32_t)f2bf(hnew[4]) | ((uint32_t)f2bf(hnew[5]) << 16);
    const uint32_t p3 = (uint32_t)f2bf(hnew[6]) | ((uint32_t)f2bf(hnew[7]) << 16);
    *(uint4*)(Hb + (size_t)node * (TH * HID) + t * HID + j0) = make_uint4(p0, p1, p2, p3);
}

// after encoder: xn0 = fc(h_final); y1 for decoder t=0
__global__ __launch_bounds__(256) void k_fc(
    const float* __restrict__ h_in, const float* __restrict__ fc_w,
    const float* __restrict__ fc_b, const float* __restrict__ feat,
    const float* __restrict__ cw1, float* __restrict__ xn_buf,
    float* __restrict__ y1)
{
    const int node = blockIdx.x * 256 + threadIdx.x;
    if (node >= NODES) return;
    const float4* h4 = (const float4*)h_in;
    const float4* w4 = (const float4*)fc_w;
    float acc = fc_b[0];
    #pragma unroll 8
    for (int kq = 0; kq < 16; kq++) {
        const float4 v = h4[(size_t)kq * NODES + node];
        const float4 w = w4[kq];
        acc = fmaf(w.x, v.x, acc);
        acc = fmaf(w.y, v.y, acc);
        acc = fmaf(w.z, v.z, acc);
        acc = fmaf(w.w, v.w, acc);
    }
    xn_buf[node] = acc;
    const int b = node / NN, n = node - b * NN;
    const float* fp = feat + ((size_t)(b * TT + TH) * NN + n) * NF;
    float yy = acc * cw1[0];
    #pragma unroll
    for (int c = 0; c < NF; c++) yy += fp[c] * cw1[1 + c];
    y1[node] = yy;
}

// ---------------- decoder kernels ----------------
// CSR gather: 4 lanes per node, interleaved edge walk, shuffle-reduce.
__global__ __launch_bounds__(256) void k_gather(
    const int* __restrict__ row0, const int* __restrict__ csrc,
    const float* __restrict__ cnrm, const float* __restrict__ y1,
    float* __restrict__ tx)
{
    const int tid  = blockIdx.x * 256 + threadIdx.x;
    const int node = tid >> 2;
    const int q    = tid & 3;
    if (node >= NODES) return;
    const int beg = row0[node], end = row0[node + 1];
    float acc = 0.f;
    for (int i = beg + q; i < end; i += 4)
        acc = fmaf(cnrm[i], y1[csrc[i]], acc);
    acc += __shfl_xor(acc, 1, 64);
    acc += __shfl_xor(acc, 2, 64);
    if (q == 0) tx[node] = acc;
}

__global__ __launch_bounds__(256) void k_dgru(
    const float* __restrict__ feat,
    const float* __restrict__ w_ih, const float* __restrict__ Wt,
    const float* __restrict__ b_ih, const float* __restrict__ b_hh,
    const float* __restrict__ w0, const float* __restrict__ cb,
    const float* __restrict__ xn_buf, const float* __restrict__ tx,
    const float* __restrict__ h_in, float* __restrict__ h_out,
    float* __restrict__ h_nm, int t)
{
    int c, jg;
    swz(blockIdx.x, c, jg);
    const int node = c * 256 + threadIdx.x;
    if (node >= NODES) return;
    const int j0 = jg * 8;

    float accr[8], accz[8], accn[8];
    #pragma unroll
    for (int m = 0; m < 8; m++) {
        accr[m] = b_hh[j0 + m];
        accz[m] = b_hh[64 + j0 + m];
        accn[m] = b_hh[128 + j0 + m];
    }
    const float4* h4 = (const float4*)h_in;
    #pragma unroll 8
    for (int kq = 0; kq < 16; kq++) {
        const float4 hv = h4[(size_t)kq * NODES + node];
        const float hk[4] = {hv.x, hv.y, hv.z, hv.w};
        #pragma unroll
        for (int u = 0; u < 4; u++) {
            const int k = kq * 4 + u;
            const float* w = Wt + k * 192 + j0;
            #pragma unroll
            for (int m = 0; m < 8; m++) {
                accr[m] = fmaf(w[m],       hk[u], accr[m]);
                accz[m] = fmaf(w[64 + m],  hk[u], accz[m]);
                accn[m] = fmaf(w[128 + m], hk[u], accn[m]);
            }
        }
    }

    const int b = node / NN, n = node - b * NN;
    const float xnv = xn_buf[node];
    float f[NF];
    const float* fp = feat + ((size_t)(b * TT + TH + t) * NN + n) * NF;
    #pragma unroll
    for (int q = 0; q < NF; q++) f[q] = fp[q];

    float xw0 = xnv * w0[0];
    #pragma unroll
    for (int q = 0; q < NF; q++) xw0 = fmaf(f[q], w0[1 + q], xw0);
    const float xg = sigmoidf_(xw0 + tx[node] + cb[0]);

    const float4 hold0 = h4[(size_t)(2 * jg)     * NODES + node];
    const float4 hold1 = h4[(size_t)(2 * jg + 1) * NODES + node];
    const float holdv[8] = {hold0.x, hold0.y, hold0.z, hold0.w,
                            hold1.x, hold1.y, hold1.z, hold1.w};
    float hnew[8];
    #pragma unroll
    for (int m = 0; m < 8; m++) {
        const int j = j0 + m;
        const float* ir  = w_ih + j * 10;
        const float* iz  = w_ih + (64 + j) * 10;
        const float* in_ = w_ih + (128 + j) * 10;
        float gr = b_ih[j]       + ir[0] * xnv;
        float gz = b_ih[64 + j]  + iz[0] * xnv;
        float gn = b_ih[128 + j] + in_[0] * xnv;
        #pragma unroll
        for (int q = 0; q < NF; q++) {
            gr = fmaf(ir[1 + q],  f[q], gr);
            gz = fmaf(iz[1 + q],  f[q], gz);
            gn = fmaf(in_[1 + q], f[q], gn);
        }
        gr = fmaf(ir[9],  xg, gr);
        gz = fmaf(iz[9],  xg, gz);
        gn = fmaf(in_[9], xg, gn);

        float r   = sigmoidf_(gr + accr[m]);
        float z   = sigmoidf_(gz + accz[m]);
        float nn_ = tanhf_(gn + r * accn[m]);
        hnew[m] = (1.f - z) * nn_ + z * holdv[m];
    }
    float4* o4 = (float4*)h_out;
    o4[(size_t)(2 * jg)     * NODES + node] = make_float4(hnew[0], hnew[1], hnew[2], hnew[3]);
    o4[(size_t)(2 * jg + 1) * NODES + node] = make_float4(hnew[4], hnew[5], hnew[6], hnew[7]);
    float4* nm4 = (float4*)h_nm;
    nm4[(size_t)node * 16 + 2 * jg]     = make_float4(hnew[0], hnew[1], hnew[2], hnew[3]);
    nm4[(size_t)node * 16 + 2 * jg + 1] = make_float4(hnew[4], hnew[5], hnew[6], hnew[7]);
}

// attention + out-projection + y1 prep for next step. Wave per node.
// Vectorized: one dwordx4 load covers 8 timesteps x 8 channels per lane.
__global__ __launch_bounds__(256) void k_attn(
    const __hip_bfloat16* __restrict__ Hb, const float* __restrict__ h_nm,
    const float* __restrict__ out_w, const float* __restrict__ out_b,
    const float* __restrict__ feat, const float* __restrict__ cw1,
    float* __restrict__ xn_buf, float* __restrict__ y1,
    float* __restrict__ out, int t)
{
    const int wid  = threadIdx.x >> 6;
    const int lane = threadIdx.x & 63;
    const int node = blockIdx.x * 4 + wid;
    if (node >= NODES) return;
    const int d0 = (lane & 7) * 8;     // channel block this lane owns

    // h vector: one coalesced load, then gather own channel block via shuffles
    const float hj = h_nm[(size_t)node * HID + lane];
    float hval[8];
    #pragma unroll
    for (int q = 0; q < 8; q++) hval[q] = __shfl(hj, d0 + q, 64);

    // H rows: 3 rounds x (64 lanes x 16B) = 24 timesteps
    const uint4* Hrow = (const uint4*)(Hb + (size_t)node * (TH * HID));
    float Hf[3][8];
    float er[3];
    #pragma unroll
    for (int R = 0; R < 3; R++) {
        const uint4 v = Hrow[R * 64 + lane];
        const uint32_t u0 = v.x, u1 = v.y, u2 = v.z, u3 = v.w;
        Hf[R][0] = __uint_as_float(u0 << 16);
        Hf[R][1] = __uint_as_float(u0 & 0xffff0000u);
        Hf[R][2] = __uint_as_float(u1 << 16);
        Hf[R][3] = __uint_as_float(u1 & 0xffff0000u);
        Hf[R][4] = __uint_as_float(u2 << 16);
        Hf[R][5] = __uint_as_float(u2 & 0xffff0000u);
        Hf[R][6] = __uint_as_float(u3 << 16);
        Hf[R][7] = __uint_as_float(u3 & 0xffff0000u);
        float part = 0.f;
        #pragma unroll
        for (int q = 0; q < 8; q++) part = fmaf(Hf[R][q], hval[q], part);
        part += __shfl_xor(part, 1, 64);
        part += __shfl_xor(part, 2, 64);
        part += __shfl_xor(part, 4, 64);
        er[R] = part;   // e[8R + (lane>>3)], uniform within 8-lane group
    }

    // softmax over 24 t's distributed across 8 groups x 3 rounds
    float m = fmaxf(fmaxf(er[0], er[1]), er[2]);
    m = fmaxf(m, __shfl_xor(m, 8, 64));
    m = fmaxf(m, __shfl_xor(m, 16, 64));
    m = fmaxf(m, __shfl_xor(m, 32, 64));

    float w0_ = __expf(er[0] - m);
    float w1_ = __expf(er[1] - m);
    float w2_ = __expf(er[2] - m);
    float s = w0_ + w1_ + w2_;
    s += __shfl_xor(s, 8, 64);
    s += __shfl_xor(s, 16, 64);
    s += __shfl_xor(s, 32, 64);
    const float rs = 1.f / s;

    // weighted sum over t for this lane's channel block
    float aq[8];
    #pragma unroll
    for (int q = 0; q < 8; q++) {
        float a = w0_ * Hf[0][q];
        a = fmaf(w1_, Hf[1][q], a);
        a = fmaf(w2_, Hf[2][q], a);
        a += __shfl_xor(a, 8, 64);
        a += __shfl_xor(a, 16, 64);
        a += __shfl_xor(a, 32, 64);
        aq[q] = a * rs;
    }

    // out projection: concat(a, h) . out_w
    float part = 0.f;
    #pragma unroll
    for (int q = 0; q < 8; q++) {
        part = fmaf(out_w[d0 + q],       aq[q],   part);
        part = fmaf(out_w[HID + d0 + q], hval[q], part);
    }
    part += __shfl_xor(part, 1, 64);
    part += __shfl_xor(part, 2, 64);
    part += __shfl_xor(part, 4, 64);
    const float xnew = part + out_b[0];

    if (lane == 0) {
        const int b = node / NN, n = node - b * NN;
        out[(b * TF + t) * NN + n] = xnew;
        xn_buf[node] = xnew;
        if (t + 1 < TF) {
            const float* fp = feat + ((size_t)(b * TT + TH + t + 1) * NN + n) * NF;
            float yy = xnew * cw1[0];
            #pragma unroll
            for (int c = 0; c < NF; c++) yy += fp[c] * cw1[1 + c];
            y1[node] = yy;
        }
    }
}

// ---------------- host launch ----------------
extern "C" void kernel_launch(void* const* d_in, const int* in_sizes, int n_in,
                              void* d_out, int out_size, void* d_ws, size_t ws_size,
                              hipStream_t stream)
{
    const float* pm     = (const float*)d_in[0];
    const float* feat   = (const float*)d_in[1];
    const int*   ei     = (const int*)d_in[2];
    const float* w_ih_e = (const float*)d_in[3];
    const float* w_hh_e = (const float*)d_in[4];
    const float* b_ih_e = (const float*)d_in[5];
    const float* b_hh_e = (const float*)d_in[6];
    const float* fc_w   = (const float*)d_in[7];
    const float* fc_b   = (const float*)d_in[8];
    const float* cw0    = (const float*)d_in[9];
    const float* cw1    = (const float*)d_in[10];
    const float* cb     = (const float*)d_in[11];
    const float* w_ih_d = (const float*)d_in[12];
    const float* w_hh_d = (const float*)d_in[13];
    const float* b_ih_d = (const float*)d_in[14];
    const float* b_hh_d = (const float*)d_in[15];
    const float* out_w  = (const float*)d_in[16];
    const float* out_b  = (const float*)d_in[17];
    float* out = (float*)d_out;

    char* ws = (char*)d_ws;
    size_t off = 0;
    auto alloc = [&](size_t bytes) -> void* {
        void* p = ws + off;
        off += (bytes + 255) & ~(size_t)255;
        return p;
    };
    float* hA   = (float*)alloc(sizeof(float) * HID * NODES);
    float* hB   = (float*)alloc(sizeof(float) * HID * NODES);
    float* h_nm = (float*)alloc(sizeof(float) * HID * NODES);
    __hip_bfloat16* Hb = (__hip_bfloat16*)alloc(sizeof(__hip_bfloat16) * (size_t)NODES * TH * HID);
    float* xn   = (float*)alloc(sizeof(float) * NODES);
    float* dis  = (float*)alloc(sizeof(float) * NODES);
    float* y1   = (float*)alloc(sizeof(float) * NODES);
    float* tx   = (float*)alloc(sizeof(float) * NODES);
    float* nrm  = (float*)alloc(sizeof(float) * ETOT);
    float* WtE  = (float*)alloc(sizeof(float) * 192 * 64);
    float* WtD  = (float*)alloc(sizeof(float) * 192 * 64);
    int*   row0 = (int*)alloc(sizeof(int) * (NODES + 1));
    int*   cnt  = (int*)alloc(sizeof(int) * NODES);
    int*   csrc = (int*)alloc(sizeof(int) * ETOT);
    float* cnrm = (float*)alloc(sizeof(float) * ETOT);
    if (off > ws_size) return;  // visible failure instead of corruption

    // setup: zero h0+deg, degree -> scan -> dis -> edge norms -> CSR, transposes
    k_init<<<(HID * NODES + 255) / 256, 256, 0, stream>>>(hA, dis);
    k_deg<<<(ETOT + 255) / 256, 256, 0, stream>>>(ei, dis);
    k_scan<<<1, 256, 0, stream>>>(dis, row0, cnt);
    k_dis<<<(NODES + 255) / 256, 256, 0, stream>>>(dis);
    k_norm<<<(ETOT + 255) / 256, 256, 0, stream>>>(ei, dis, nrm);
    k_fill<<<(ETOT + 255) / 256, 256, 0, stream>>>(ei, nrm, row0, cnt, csrc, cnrm);
    k_prep<<<(192 * 64 + 255) / 256, 256, 0, stream>>>(w_hh_e, w_hh_d, WtE, WtD);

    const int gGRU = NCH * 8;   // 1024 swizzled blocks

    // encoder: ping-pong hA/hB; 24 steps ends back in hA
    for (int t = 0; t < TH; t++) {
        const float* hin = (t & 1) ? hB : hA;
        float* hout      = (t & 1) ? hA : hB;
        k_enc<<<gGRU, 256, 0, stream>>>(pm, w_ih_e, WtE, b_ih_e, b_hh_e,
                                        fc_w, fc_b, hin, hout, Hb, t);
    }
    k_fc<<<NODES / 256, 256, 0, stream>>>(hA, fc_w, fc_b, feat, cw1, xn, y1);

    // decoder
    for (int t = 0; t < TF; t++) {
        const float* hin = (t & 1) ? hB : hA;
        float* hout      = (t & 1) ? hA : hB;
        k_gather<<<(NODES * 4) / 256, 256, 0, stream>>>(row0, csrc, cnrm, y1, tx);
        k_dgru<<<gGRU, 256, 0, stream>>>(feat, w_ih_d, WtD, b_ih_d, b_hh_d,
                                         cw0, cb, xn, tx, hin, hout, h_nm, t);
        k_attn<<<NODES / 4, 256, 0, stream>>>(Hb, h_nm, out_w, out_b, feat, cw1,
                                              xn, y1, out, t);
    }
}